// Round 3
// baseline (441.318 us; speedup 1.0000x reference)
//
#include <hip/hip_runtime.h>

typedef float f32x4 __attribute__((ext_vector_type(4)));
typedef short s16x8 __attribute__((ext_vector_type(8)));
typedef short s16x4 __attribute__((ext_vector_type(4)));

#define NLAB 10
#define LEGO 128
#define INA  128
#define OUTC 512
#define KDIM 1152               // 9 offsets * 128 ic
#define WPITCH 34
#define XROWS 4                 // staged padded rows per block (2 output rows)
#define XL_ELEMS (XROWS * WPITCH * 128)   // 17408 shorts = 34816 B

__device__ __forceinline__ unsigned short f2bf(float f) {
    unsigned u = __builtin_bit_cast(unsigned, f);
    u += 0x7fffu + ((u >> 16) & 1u);          // round-to-nearest-even
    return (unsigned short)(u >> 16);
}
__device__ __forceinline__ float bf2f(unsigned short h) {
    return __builtin_bit_cast(float, ((unsigned)h) << 16);
}

// Fused prep: blocks 0..639 -> wt, blocks 640..641 -> sel/cs
__global__ void k_prep(const float* __restrict__ ff,
                       const float* __restrict__ coeff, const float* __restrict__ comb,
                       unsigned short* __restrict__ wt,
                       int* __restrict__ sel, float* __restrict__ cs) {
    const int gb = blockIdx.x;
    if (gb < 640) {
        int t = gb * 256 + threadIdx.x;
        if (t >= NLAB * LEGO * INA) return;
        int ic = t & 127;
        int ll = t >> 7;                       // lab*128 + l
        const float* src = ff + (size_t)(ll * 128 + ic) * 9;
        unsigned short* dst = wt + (size_t)ll * KDIM + ic;
#pragma unroll
        for (int off = 0; off < 9; ++off) dst[off * 128] = f2bf(src[off]);
        return;
    }
    int o = (gb - 640) * 256 + threadIdx.x;
    if (o >= OUTC) return;
    const float* row = comb + (size_t)o * LEGO;
    float best = row[0]; int bi = 0;
    for (int l = 1; l < LEGO; ++l) { float v = row[l]; if (v > best) { best = v; bi = l; } }
    sel[o] = bi;
    cs[o] = coeff[(size_t)o * LEGO + bi];
}

// Small-tile conv: block = (b, nt), nt in 0..15 -> output rows h0=2*nt, h0+1 (64 px).
// 2048 blocks, LDS 34.8KB+4KB -> 4 blocks/CU: phases (stage/GEMM/store) are half
// as long as the 128-px version and 2x as many blocks interleave them.
__global__ __launch_bounds__(256, 4) void k_conv2(
    const float* __restrict__ x, const int* __restrict__ label,
    const unsigned short* __restrict__ wt,
    const int* __restrict__ sel, const float* __restrict__ cs,
    float* __restrict__ out)
{
    __shared__ unsigned short xl[XL_ELEMS];   // x tile (swizzled); later aliased as feat [128][68]
    __shared__ int   s_sel[OUTC];
    __shared__ float s_cs[OUTC];

    const int t  = threadIdx.x;
    const int b  = blockIdx.y;
    const int nt = blockIdx.x;                // 0..15
    const int h0 = nt * 2;

    // sel/cs -> LDS (epilogue gather becomes LDS-fast)
    for (int i = t; i < OUTC; i += 256) { s_sel[i] = sel[i]; s_cs[i] = cs[i]; }

    {   // zero x tile (halo rows / border cols rely on this)
        uint4* z = (uint4*)xl;
        for (int i = t; i < XL_ELEMS / 8; i += 256) z[i] = make_uint4(0u,0u,0u,0u);
    }
    __syncthreads();

    const int lab = label[b];

    // stage rows h0-1 .. h0+2, layout [row][w1][ic] with 16B XOR swizzle on ic-chunk
    for (int i = t; i < 4096; i += 256) {
        int wq  = i & 7;
        int ri  = i >> 3;                     // 0..511
        int row = ri & 3;
        int ic  = ri >> 2;
        int h = h0 - 1 + row;
        if (h >= 0 && h < 32) {
            const f32x4 v = *(const f32x4*)(x + (((size_t)b * INA + ic) << 10) + h * 32 + wq * 4);
            int icl = ic & 7, ich = ic >> 3;
#pragma unroll
            for (int j = 0; j < 4; ++j) {
                int w1 = wq * 4 + j + 1;      // 1..32 (cols 0,33 stay zero)
                int el = (row * WPITCH + w1) * 128 + (((ich ^ (w1 & 15)) << 3) | icl);
                xl[el] = f2bf(v[j]);
            }
        }
    }
    __syncthreads();

    const int lane = t & 63;
    const int wv   = t >> 6;
    const int l16  = lane & 15;
    const int quad = lane >> 4;
    const int m_base = wv << 5;               // wave owns 32 l-rows: no A duplication

    const unsigned short* wl = wt + (size_t)lab * (LEGO * KDIM);
    const unsigned short* arow[2];
#pragma unroll
    for (int mi = 0; mi < 2; ++mi)
        arow[mi] = wl + (size_t)(m_base + mi*16 + l16) * KDIM + quad * 8;

    int prow[4], pcol[4];
#pragma unroll
    for (int ni = 0; ni < 4; ++ni) {
        int p = ni*16 + l16;                  // local pixel 0..63
        prow[ni] = p >> 5;                    // 0..1
        pcol[ni] = p & 31;
    }

    f32x4 acc[2][4];
    {
        f32x4 zz = {0.f, 0.f, 0.f, 0.f};
#pragma unroll
        for (int mi = 0; mi < 2; ++mi)
#pragma unroll
            for (int ni = 0; ni < 4; ++ni) acc[mi][ni] = zz;
    }

    // 4-deep A-prefetch ring (distance 3 ~ 120 issue-cycles of cover for L2 latency)
    s16x8 ap[4][2];
#pragma unroll
    for (int s = 0; s < 3; ++s)
#pragma unroll
        for (int mi = 0; mi < 2; ++mi)
            ap[s][mi] = *(const s16x8*)(arow[mi] + s * 32);

#pragma unroll
    for (int off = 0; off < 9; ++off) {
        const int dh = off / 3 - 1;
        const int dw = off % 3 - 1;
        int bbase[4], bsw[4];
#pragma unroll
        for (int ni = 0; ni < 4; ++ni) {
            int row = prow[ni] + dh + 1;      // 0..3, always staged
            int w1  = pcol[ni] + dw + 1;      // 0..33, borders are zeros
            bbase[ni] = (row * WPITCH + w1) * 128;
            bsw[ni]   = w1 & 15;
        }
#pragma unroll
        for (int kc = 0; kc < 4; ++kc) {
            const int step = off * 4 + kc;
            if (step + 3 < 36) {              // prefetch A for step+3
#pragma unroll
                for (int mi = 0; mi < 2; ++mi)
                    ap[(step + 3) & 3][mi] = *(const s16x8*)(arow[mi] + (step + 3) * 32);
            }
            const int jj = kc * 4 + quad;
            s16x8 bb[4];
#pragma unroll
            for (int ni = 0; ni < 4; ++ni)
                bb[ni] = *(const s16x8*)(xl + bbase[ni] + ((jj ^ bsw[ni]) << 3)); // ds_read_b128
            const s16x8* a = ap[step & 3];
#pragma unroll
            for (int mi = 0; mi < 2; ++mi)
#pragma unroll
                for (int ni = 0; ni < 4; ++ni)
                    acc[mi][ni] = __builtin_amdgcn_mfma_f32_16x16x32_bf16(a[mi], bb[ni], acc[mi][ni], 0, 0, 0);
        }
    }

    __syncthreads();                          // all LDS x reads done; reuse as feat
    unsigned short* featb = xl;               // feat bf16 [128][68] (pad breaks quad collisions)
#pragma unroll
    for (int mi = 0; mi < 2; ++mi)
#pragma unroll
        for (int ni = 0; ni < 4; ++ni) {
            int n = ni*16 + l16;
#pragma unroll
            for (int r = 0; r < 4; ++r) {
                int m = m_base + mi*16 + quad*4 + r;   // m89-verified C/D layout
                featb[m * 68 + n] = f2bf(acc[mi][ni][r]);
            }
        }
    __syncthreads();

    // out[b][o][h0*32 + p] = cs[o] * feat[sel[o]][p], p in 0..63
    const size_t obase = ((size_t)b * OUTC) * 1024 + (size_t)h0 * 32;
    for (int i = t; i < OUTC * 16; i += 256) {
        int pg = i & 15;                      // 16 px-groups of 4
        int o  = i >> 4;
        int so = s_sel[o];
        float cc = s_cs[o];
        s16x4 fv = *(const s16x4*)(featb + so * 68 + pg * 4);
        f32x4 ov;
#pragma unroll
        for (int j = 0; j < 4; ++j)
            ov[j] = cc * bf2f((unsigned short)fv[j]);
        __builtin_nontemporal_store(ov, (f32x4*)(out + obase + (size_t)o * 1024 + pg * 4));
    }
}

extern "C" void kernel_launch(void* const* d_in, const int* in_sizes, int n_in,
                              void* d_out, int out_size, void* d_ws, size_t ws_size,
                              hipStream_t stream) {
    const float* x     = (const float*)d_in[0];
    const int*   label = (const int*)d_in[1];
    const float* ff    = (const float*)d_in[2];
    const float* coeff = (const float*)d_in[3];   // second_filter_coefficients (use [0] slice)
    const float* comb  = (const float*)d_in[4];   // second_filter_combination  (use [0] slice)
    float* out = (float*)d_out;

    char* ws = (char*)d_ws;
    unsigned short* wt  = (unsigned short*)ws;              // 10*128*1152*2 = 2,949,120 B
    int*   sel = (int*)(ws + 2949120);                      // 2 KB
    float* cs  = (float*)(ws + 2949120 + 2048);             // 2 KB   (total 2,953,216 B: known-safe)

    k_prep <<<642, 256, 0, stream>>>(ff, coeff, comb, wt, sel, cs);
    k_conv2<<<dim3(16, 128), 256, 0, stream>>>(x, label, wt, sel, cs, out);
}

// Round 4
// 406.451 us; speedup vs baseline: 1.0858x; 1.0858x over previous
//
#include <hip/hip_runtime.h>

typedef float f32x4 __attribute__((ext_vector_type(4)));
typedef short s16x8 __attribute__((ext_vector_type(8)));
typedef short s16x4 __attribute__((ext_vector_type(4)));

#define NLAB 10
#define LEGO 128
#define INA  128
#define OUTC 512
#define KDIM 1152               // 9 offsets * 128 ic
#define WPITCH 34
#define XL_ELEMS (6*34*128)     // 26112 bf16 = 52224 B

__device__ __forceinline__ unsigned short f2bf(float f) {
    unsigned u = __builtin_bit_cast(unsigned, f);
    u += 0x7fffu + ((u >> 16) & 1u);          // round-to-nearest-even
    return (unsigned short)(u >> 16);
}
__device__ __forceinline__ float bf2f(unsigned short h) {
    return __builtin_bit_cast(float, ((unsigned)h) << 16);
}

// Fused prep: blocks 0..639 -> wt, blocks 640..641 -> sel/cs
__global__ void k_prep(const float* __restrict__ ff,
                       const float* __restrict__ coeff, const float* __restrict__ comb,
                       unsigned short* __restrict__ wt,
                       int* __restrict__ sel, float* __restrict__ cs) {
    const int gb = blockIdx.x;
    if (gb < 640) {
        int t = gb * 256 + threadIdx.x;
        if (t >= NLAB * LEGO * INA) return;
        int ic = t & 127;
        int ll = t >> 7;                       // lab*128 + l
        const float* src = ff + (size_t)(ll * 128 + ic) * 9;
        unsigned short* dst = wt + (size_t)ll * KDIM + ic;
#pragma unroll
        for (int off = 0; off < 9; ++off) dst[off * 128] = f2bf(src[off]);
        return;
    }
    int o = (gb - 640) * 256 + threadIdx.x;
    if (o >= OUTC) return;
    const float* row = comb + (size_t)o * LEGO;
    float best = row[0]; int bi = 0;
    for (int l = 1; l < LEGO; ++l) { float v = row[l]; if (v > best) { best = v; bi = l; } }
    sel[o] = bi;
    cs[o] = coeff[(size_t)o * LEGO + bi];
}

// 128-px tile (verified structure; 512B-contiguous output chunks per o-row).
// Staging rewritten: per thread owns (row, ic-group, w-quad) -> 8 coalesced
// f32x4 loads, then 4 dense ds_write_b128 (full 16B ic-chunks, all 32 banks
// hit exactly 8x per instr = conflict-free-dense). Replaces the 32-way
// conflicted ds_write_u16 scatter (= the measured 1.2e7 conflict cycles).
__global__ __launch_bounds__(256, 3) void k_conv(
    const float* __restrict__ x, const int* __restrict__ label,
    const unsigned short* __restrict__ wt,
    const int* __restrict__ sel, const float* __restrict__ cs,
    float* __restrict__ out)
{
    __shared__ unsigned short xl[XL_ELEMS];   // staged x (swizzled); later aliased as feat bf16 [128][132]

    const int t  = threadIdx.x;
    const int b  = blockIdx.y;
    const int nt = blockIdx.x;                // 0..7 -> pixel rows h0..h0+3
    const int h0 = nt * 4;

    // ---- zero only what staging won't write (disjoint -> no barrier needed) --
    {
        s16x8 zz = {0,0,0,0,0,0,0,0};
        if (t < 192) {                        // border cols w1=0,33: 6 rows x 2 x 16 chunks
            int row = t >> 5;
            int c   = (t >> 1) & 15;
            int w1  = (t & 1) ? 33 : 0;
            *(s16x8*)(xl + (row * WPITCH + w1) * 128 + c * 8) = zz;
        }
        if (nt == 0)                          // row0 (h=-1) fully zero
            for (int i = t; i < 544; i += 256)
                *(s16x8*)(xl + (0 * WPITCH + (i >> 4)) * 128 + (i & 15) * 8) = zz;
        if (nt == 7)                          // row5 (h=32) fully zero
            for (int i = t; i < 544; i += 256)
                *(s16x8*)(xl + (5 * WPITCH + (i >> 4)) * 128 + (i & 15) * 8) = zz;
    }

    const int lab = label[b];

    // ---- stage interior: 768 tasks = (row 0..5, g 0..15, wq 0..7), 3/thread --
    for (int it = 0; it < 3; ++it) {
        int idx = t + it * 256;
        int wq  = idx & 7;
        int gg  = (idx >> 3) & 15;            // ic-group (8 ic)
        int row = idx >> 7;                   // wave-uniform
        int h = h0 - 1 + row;
        if (h >= 0 && h < 32) {
            f32x4 vv[8];
            const float* xb = x + ((size_t)b * INA) * 1024 + h * 32 + wq * 4;
#pragma unroll
            for (int k = 0; k < 8; ++k)       // coalesced: 8 lanes x 16B per ic row
                vv[k] = *(const f32x4*)(xb + (size_t)(gg * 8 + k) * 1024);
#pragma unroll
            for (int j = 0; j < 4; ++j) {
                int w1 = wq * 4 + j + 1;      // 1..32
                int c  = gg ^ (w1 & 15);      // GEMM-read swizzle preserved
                s16x8 o;
#pragma unroll
                for (int k = 0; k < 8; ++k) o[k] = (short)f2bf(vv[k][j]);
                *(s16x8*)(xl + (row * WPITCH + w1) * 128 + c * 8) = o;  // dense b128
            }
        }
    }

    const int lane = t & 63;
    const int wv   = t >> 6;
    const int l16  = lane & 15;
    const int quad = lane >> 4;
    const int m_base = (wv & 1) << 6;
    const int n_base = (wv >> 1) << 6;

    const unsigned short* wl = wt + (size_t)lab * (LEGO * KDIM);
    const unsigned short* arow[4];
#pragma unroll
    for (int mi = 0; mi < 4; ++mi)
        arow[mi] = wl + (size_t)(m_base + mi*16 + l16) * KDIM + quad * 8;

    int prow[4], pcol[4];
#pragma unroll
    for (int ni = 0; ni < 4; ++ni) {
        int p = n_base + ni*16 + l16;
        prow[ni] = p >> 5;
        pcol[ni] = p & 31;
    }

    f32x4 acc[4][4];
    {
        f32x4 zz = {0.f, 0.f, 0.f, 0.f};
#pragma unroll
        for (int mi = 0; mi < 4; ++mi)
#pragma unroll
            for (int ni = 0; ni < 4; ++ni) acc[mi][ni] = zz;
    }

    // preload A ring for steps 0,1 (independent of LDS staging -> overlaps)
    s16x8 ap[3][4];
#pragma unroll
    for (int s = 0; s < 2; ++s)
#pragma unroll
        for (int mi = 0; mi < 4; ++mi)
            ap[s][mi] = *(const s16x8*)(arow[mi] + s * 32);

    __syncthreads();                          // staged tile ready

#pragma unroll
    for (int off = 0; off < 9; ++off) {
        const int dh = off / 3 - 1;
        const int dw = off % 3 - 1;
        int bbase[4], bsw[4];
#pragma unroll
        for (int ni = 0; ni < 4; ++ni) {
            int row = prow[ni] + dh + 1;      // 0..5, always staged
            int w1  = pcol[ni] + dw + 1;      // 0..33, borders are zeros
            bbase[ni] = (row * WPITCH + w1) * 128;
            bsw[ni]   = w1 & 15;
        }
#pragma unroll
        for (int kc = 0; kc < 4; ++kc) {
            const int step = off * 4 + kc;
            if (step + 2 < 36) {              // prefetch A for step+2
#pragma unroll
                for (int mi = 0; mi < 4; ++mi)
                    ap[(step + 2) % 3][mi] = *(const s16x8*)(arow[mi] + (step + 2) * 32);
            }
            const int jj = kc * 4 + quad;
            s16x8 bb[4];
#pragma unroll
            for (int ni = 0; ni < 4; ++ni)
                bb[ni] = *(const s16x8*)(xl + bbase[ni] + ((jj ^ bsw[ni]) << 3)); // ds_read_b128
            const s16x8* a = ap[step % 3];
#pragma unroll
            for (int mi = 0; mi < 4; ++mi)
#pragma unroll
                for (int ni = 0; ni < 4; ++ni)
                    acc[mi][ni] = __builtin_amdgcn_mfma_f32_16x16x32_bf16(a[mi], bb[ni], acc[mi][ni], 0, 0, 0);
        }
    }

    __syncthreads();                          // all LDS x reads done; reuse as feat
    unsigned short* featb = xl;               // feat bf16 [128][132] (pad breaks quad collisions)
#pragma unroll
    for (int mi = 0; mi < 4; ++mi)
#pragma unroll
        for (int ni = 0; ni < 4; ++ni) {
            int n = n_base + ni*16 + l16;
#pragma unroll
            for (int r = 0; r < 4; ++r) {
                int m = m_base + mi*16 + quad*4 + r;   // m89-verified C/D layout
                featb[m * 132 + n] = f2bf(acc[mi][ni][r]);
            }
        }
    __syncthreads();

    // out[b][o][nt*128 + p] = c[o] * feat[sel[o]][p]; 512B contiguous per o-row
    const size_t obase = ((size_t)b * OUTC) * 1024 + (size_t)nt * 128;
    for (int i = t; i < OUTC * 32; i += 256) {
        int pg = i & 31;
        int o  = i >> 5;
        int so = sel[o];
        float cc = cs[o];
        s16x4 fv = *(const s16x4*)(featb + so * 132 + pg * 4);
        f32x4 ov;
#pragma unroll
        for (int j = 0; j < 4; ++j)
            ov[j] = cc * bf2f((unsigned short)fv[j]);
        __builtin_nontemporal_store(ov, (f32x4*)(out + obase + (size_t)o * 1024 + pg * 4));
    }
}

extern "C" void kernel_launch(void* const* d_in, const int* in_sizes, int n_in,
                              void* d_out, int out_size, void* d_ws, size_t ws_size,
                              hipStream_t stream) {
    const float* x     = (const float*)d_in[0];
    const int*   label = (const int*)d_in[1];
    const float* ff    = (const float*)d_in[2];
    const float* coeff = (const float*)d_in[3];   // second_filter_coefficients (use [0] slice)
    const float* comb  = (const float*)d_in[4];   // second_filter_combination  (use [0] slice)
    float* out = (float*)d_out;

    char* ws = (char*)d_ws;
    unsigned short* wt  = (unsigned short*)ws;              // 10*128*1152*2 = 2,949,120 B
    int*   sel = (int*)(ws + 2949120);                      // 2 KB
    float* cs  = (float*)(ws + 2949120 + 2048);             // 2 KB   (total 2,953,216 B: known-safe)

    k_prep<<<642, 256, 0, stream>>>(ff, coeff, comb, wt, sel, cs);
    k_conv<<<dim3(8, 128), 256, 0, stream>>>(x, label, wt, sel, cs, out);
}